// Round 2
// baseline (622.475 us; speedup 1.0000x reference)
//
#include <hip/hip_runtime.h>

#define NN 4096
#define IDX_CAP 512
#define SEG_CAP 160
#define SLOPE 0.2f

typedef float f4_t __attribute__((ext_vector_type(4)));

// ---- workspace layout (float offsets unless noted) ----
#define V_OFF     0                        // v1i,v2i,v1s,v2s : 4*128
#define C_OFF     512                      // 4 score constants
#define BT_OFF    516                      // b_total[128]
#define S_OFF     1024                     // s1i,s2i,s1s,s2s : 4*4096
#define HXI_OFF   32768                    // Ld@x   [4096,128]
#define HXS_OFF   (HXI_OFF + NN*128)       // Lu@x
#define UI_OFF    (HXS_OFF + NN*128)       // x@Wi0 + Hxi@Wi1
#define US_OFF    (UI_OFF + NN*128)        // x@Ws0 + Hxs@Ws1
#define XWH_OFF   (US_OFF + NN*128)        // x@Wh
#define OI_OFF    (XWH_OFF + NN*128)       // alpha_irr @ U_irr
#define OS_OFF    (OI_OFF + NN*128)        // alpha_sol @ U_sol
#define ZP_OFF    (OS_OFF + NN*128)        // P@xWh split-K partials: 8 * [4096,128]
#define WS_FLOATS (ZP_OFF + 8*NN*128)
#define IDX_BYTE_OFF ((size_t)WS_FLOATS * 4)                  // u16 idx lists: 2*4096*512
#define CNT_BYTE_OFF (IDX_BYTE_OFF + (size_t)2*NN*IDX_CAP*2)  // int counts: 2*4096
// total ws ≈ 38.2 MiB

// Xt column map: insert 4-float pad after every 32 floats -> stride-8-float
// float4 reads go from 4-way bank conflict to <=2-way (free, m136).
#define XI(c) ((c) + (((c) >> 5) << 2))   // c in [0,128) -> [0,140)

struct SmemGemm { float Pt[64][33]; float Xt[32][140]; };          // 26368 B
struct SmemSpmm {
  short jseg[4][SEG_CAP]; float vseg[4][SEG_CAP];
  int wcnt[4]; int off[5];
  short jl[IDX_CAP]; float vl[IDX_CAP]; float red[4][128];
};
struct SmemAttn {
  int jl[IDX_CAP]; float el[IDX_CAP]; float red[4][128];
  float rsum[256]; float dsh[4];
};
union SmemU { SmemGemm g; SmemSpmm s; SmemAttn a; };

// ---------------------------------------------------------------------------
// Prep: v-vectors so s1[i] = x[i,:]·v + c, b_total.
__global__ __launch_bounds__(128) void k_prep(
    const float* __restrict__ Wi_w, const float* __restrict__ Wi_b,
    const float* __restrict__ Ws_w, const float* __restrict__ Ws_b,
    const float* __restrict__ Wh_b, const float* __restrict__ att_irr,
    const float* __restrict__ att_sol, float* __restrict__ ws) {
  const int t = threadIdx.x;
  float v1i = 0.f, v2i = 0.f, v1s = 0.f, v2s = 0.f;
  for (int j = 0; j < 2; ++j) {
    for (int o = 0; o < 128; ++o) {
      const float wi = Wi_w[j*16384 + t*128 + o];
      const float wv = Ws_w[j*16384 + t*128 + o];
      v1i += wi * att_irr[j*128 + o];
      v2i += wi * att_irr[256 + j*128 + o];
      v1s += wv * att_sol[j*128 + o];
      v2s += wv * att_sol[256 + j*128 + o];
    }
  }
  ws[V_OFF + t]       = v1i;
  ws[V_OFF + 128 + t] = v2i;
  ws[V_OFF + 256 + t] = v1s;
  ws[V_OFF + 384 + t] = v2s;
  ws[BT_OFF + t] = Wi_b[t] + Wi_b[128 + t] + Ws_b[t] + Ws_b[128 + t] + Wh_b[t];
  if (t < 4) {
    const float* bb = (t < 2) ? Wi_b : Ws_b;
    const float* aa = ((t < 2) ? att_irr : att_sol) + ((t & 1) ? 256 : 0);
    float c = 0.f;
    for (int k = 0; k < 256; ++k) c += bb[k] * aa[k];
    ws[C_OFF + t] = c;
  }
}

// ---------------------------------------------------------------------------
// Fused pre-pass: blocks 0..127 compute xWh = x@Wh (BM=32 GEMM);
// blocks 128..1151 compute the 4 attention score dots (one wave per row).
__global__ __launch_bounds__(256) void k_pre2(
    const float* __restrict__ x, const float* __restrict__ Wh_w,
    float* __restrict__ ws) {
  __shared__ __align__(16) float At[32][33];
  __shared__ __align__(16) float Wt[32][132];
  const int t = threadIdx.x;

  if (blockIdx.x < 128) {
    // ---- xWh GEMM ----
    const int rb = blockIdx.x;
    float* out = ws + XWH_OFF;
    const int rg = t >> 4, cg = t & 15;
    const int r0 = rb * 32;
    float acc[2][8];
    #pragma unroll
    for (int i = 0; i < 2; ++i)
      #pragma unroll
      for (int j = 0; j < 8; ++j) acc[i][j] = 0.f;
    for (int k0 = 0; k0 < 128; k0 += 32) {
      __syncthreads();
      {
        const int row = t >> 3, kq = t & 7;
        const float4 av = *(const float4*)&x[(r0 + row)*128 + k0 + kq*4];
        At[row][kq*4+0] = av.x; At[row][kq*4+1] = av.y;
        At[row][kq*4+2] = av.z; At[row][kq*4+3] = av.w;
      }
      #pragma unroll
      for (int l = 0; l < 4; ++l) {
        const int idx = t + l*256;
        const int kr = idx >> 5, c4 = idx & 31;
        const float4 wv = *(const float4*)&Wh_w[(k0 + kr)*128 + c4*4];
        Wt[kr][c4*4+0] = wv.x; Wt[kr][c4*4+1] = wv.y;
        Wt[kr][c4*4+2] = wv.z; Wt[kr][c4*4+3] = wv.w;
      }
      __syncthreads();
      #pragma unroll
      for (int k = 0; k < 32; ++k) {
        const float a0 = At[rg*2 + 0][k];
        const float a1 = At[rg*2 + 1][k];
        const float4 b0 = *(const float4*)&Wt[k][cg*8];
        const float4 b1 = *(const float4*)&Wt[k][cg*8 + 4];
        acc[0][0] += a0*b0.x; acc[0][1] += a0*b0.y; acc[0][2] += a0*b0.z; acc[0][3] += a0*b0.w;
        acc[0][4] += a0*b1.x; acc[0][5] += a0*b1.y; acc[0][6] += a0*b1.z; acc[0][7] += a0*b1.w;
        acc[1][0] += a1*b0.x; acc[1][1] += a1*b0.y; acc[1][2] += a1*b0.z; acc[1][3] += a1*b0.w;
        acc[1][4] += a1*b1.x; acc[1][5] += a1*b1.y; acc[1][6] += a1*b1.z; acc[1][7] += a1*b1.w;
      }
    }
    #pragma unroll
    for (int i = 0; i < 2; ++i) {
      const int r = r0 + rg*2 + i;
      #pragma unroll
      for (int j = 0; j < 8; ++j) out[r*128 + cg*8 + j] = acc[i][j];
    }
  } else {
    // ---- scores ----
    const int wave = t >> 6, lane = t & 63;
    const int row = (blockIdx.x - 128) * 4 + wave;
    const float* v = ws + V_OFF;
    const float x0 = x[row*128 + lane];
    const float x1 = x[row*128 + 64 + lane];
    float p0 = x0 * v[lane]       + x1 * v[64 + lane];
    float p1 = x0 * v[128 + lane] + x1 * v[192 + lane];
    float p2 = x0 * v[256 + lane] + x1 * v[320 + lane];
    float p3 = x0 * v[384 + lane] + x1 * v[448 + lane];
    #pragma unroll
    for (int off = 32; off; off >>= 1) {
      p0 += __shfl_down(p0, off);
      p1 += __shfl_down(p1, off);
      p2 += __shfl_down(p2, off);
      p3 += __shfl_down(p3, off);
    }
    if (lane == 0) {
      ws[S_OFF + row]          = p0 + ws[C_OFF + 0];
      ws[S_OFF + NN + row]     = p1 + ws[C_OFF + 1];
      ws[S_OFF + 2*NN + row]   = p2 + ws[C_OFF + 2];
      ws[S_OFF + 3*NN + row]   = p3 + ws[C_OFF + 3];
    }
  }
}

// ---------------------------------------------------------------------------
// P-GEMM body: BM=64, BN=128, BK=32, 4x8 thread tile, padded Xt (<=2-way).
__device__ __forceinline__ void pgemm_body(
    const float* __restrict__ P, const float* __restrict__ Xw,
    float* __restrict__ zpart, SmemU& sm, const int rbl, const int kz) {
  const int t = threadIdx.x;
  const int rg = t >> 4, cg = t & 15;
  const int r0 = rbl * 64;
  const int kbase = kz * 512;
  float acc[4][8];
  #pragma unroll
  for (int i = 0; i < 4; ++i)
    #pragma unroll
    for (int j = 0; j < 8; ++j) acc[i][j] = 0.f;

  for (int k0 = kbase; k0 < kbase + 512; k0 += 32) {
    __syncthreads();
    #pragma unroll
    for (int l = 0; l < 2; ++l) { // stage P: 64x32
      const int idx = t + l*256;
      const int row = idx >> 3, kq = idx & 7;
      const float4 pv = *(const float4*)&P[(size_t)(r0 + row)*NN + k0 + kq*4];
      sm.g.Pt[row][kq*4+0] = pv.x; sm.g.Pt[row][kq*4+1] = pv.y;
      sm.g.Pt[row][kq*4+2] = pv.z; sm.g.Pt[row][kq*4+3] = pv.w;
    }
    #pragma unroll
    for (int l = 0; l < 4; ++l) { // stage xWh: 32x128 (padded layout)
      const int idx = t + l*256;
      const int kr = idx >> 5, c4 = idx & 31;
      const float4 xv = *(const float4*)&Xw[(k0 + kr)*128 + c4*4];
      *(float4*)&sm.g.Xt[kr][XI(c4*4)] = xv;
    }
    __syncthreads();
    #pragma unroll
    for (int k = 0; k < 32; ++k) {
      const float a0 = sm.g.Pt[rg*4 + 0][k];
      const float a1 = sm.g.Pt[rg*4 + 1][k];
      const float a2 = sm.g.Pt[rg*4 + 2][k];
      const float a3 = sm.g.Pt[rg*4 + 3][k];
      const float4 b0 = *(const float4*)&sm.g.Xt[k][XI(cg*8)];
      const float4 b1 = *(const float4*)&sm.g.Xt[k][XI(cg*8 + 4)];
      acc[0][0] += a0*b0.x; acc[0][1] += a0*b0.y; acc[0][2] += a0*b0.z; acc[0][3] += a0*b0.w;
      acc[0][4] += a0*b1.x; acc[0][5] += a0*b1.y; acc[0][6] += a0*b1.z; acc[0][7] += a0*b1.w;
      acc[1][0] += a1*b0.x; acc[1][1] += a1*b0.y; acc[1][2] += a1*b0.z; acc[1][3] += a1*b0.w;
      acc[1][4] += a1*b1.x; acc[1][5] += a1*b1.y; acc[1][6] += a1*b1.z; acc[1][7] += a1*b1.w;
      acc[2][0] += a2*b0.x; acc[2][1] += a2*b0.y; acc[2][2] += a2*b0.z; acc[2][3] += a2*b0.w;
      acc[2][4] += a2*b1.x; acc[2][5] += a2*b1.y; acc[2][6] += a2*b1.z; acc[2][7] += a2*b1.w;
      acc[3][0] += a3*b0.x; acc[3][1] += a3*b0.y; acc[3][2] += a3*b0.z; acc[3][3] += a3*b0.w;
      acc[3][4] += a3*b1.x; acc[3][5] += a3*b1.y; acc[3][6] += a3*b1.z; acc[3][7] += a3*b1.w;
    }
  }
  float* __restrict__ zp = zpart + (size_t)kz * NN * 128;
  #pragma unroll
  for (int i = 0; i < 4; ++i) {
    const int r = r0 + rg*4 + i;
    #pragma unroll
    for (int j = 0; j < 8; ++j) zp[r*128 + cg*8 + j] = acc[i][j];
  }
}

// ---------------------------------------------------------------------------
// Sparse row pass body (per-wave register-base compaction + nt scan).
__device__ __forceinline__ void spmm_body(
    const float* __restrict__ Ld, const float* __restrict__ Lu,
    const float* __restrict__ x, float* __restrict__ ws,
    unsigned short* __restrict__ idxbuf, int* __restrict__ cntbuf,
    SmemU& sm, const int bx) {
  const int row = bx & (NN - 1);
  const int br  = bx >> 12;
  const float* __restrict__ Lrow = (br ? Lu : Ld) + (size_t)row * NN;
  float* __restrict__ Hx = ws + (br ? HXS_OFF : HXI_OFF);
  unsigned short* __restrict__ idxg = idxbuf + (size_t)(br*NN + row) * IDX_CAP;
  const float2* __restrict__ x2 = (const float2*)x;
  const int t = threadIdx.x;
  const int w = t >> 6, lane = t & 63;
  const unsigned long long lmask = (1ull << lane) - 1ull;

  const f4_t* __restrict__ Lrow4 = (const f4_t*)Lrow;
  f4_t lv[4];
  #pragma unroll
  for (int i = 0; i < 4; ++i) lv[i] = __builtin_nontemporal_load(&Lrow4[i*256 + t]);

  int base = 0;
  #pragma unroll
  for (int i = 0; i < 4; ++i) {
    #pragma unroll
    for (int c = 0; c < 4; ++c) {
      const float v = lv[i][c];
      const unsigned long long bm = __ballot(v != 0.f);
      if (v != 0.f) {
        const int pos = base + (int)__popcll(bm & lmask);
        if (pos < SEG_CAP) {
          sm.s.jseg[w][pos] = (short)((i*256 + t)*4 + c);
          sm.s.vseg[w][pos] = v;
        }
      }
      base += (int)__popcll(bm);
    }
  }
  if (lane == 0) sm.s.wcnt[w] = base;
  __syncthreads();
  if (t == 0) {
    int o = 0, ov = 0;
    #pragma unroll
    for (int s = 0; s < 4; ++s) { sm.s.off[s] = o; ov |= (sm.s.wcnt[s] > SEG_CAP); o += sm.s.wcnt[s]; }
    sm.s.off[4] = (ov || o > IDX_CAP) ? (IDX_CAP + 1) : o;
    cntbuf[br*NN + row] = sm.s.off[4];
  }
  __syncthreads();
  const int m = sm.s.off[4];

  if (m <= IDX_CAP) {
    const int o = sm.s.off[w], c = sm.s.wcnt[w];
    for (int k = lane; k < c; k += 64) {
      const short j = sm.s.jseg[w][k];
      sm.s.jl[o + k] = j;
      sm.s.vl[o + k] = sm.s.vseg[w][k];
      idxg[o + k] = (unsigned short)j;
    }
  }
  __syncthreads();

  float acc0 = 0.f, acc1 = 0.f;
  if (m <= IDX_CAP) {
    int p = w;
    for (; p + 28 < m; p += 32) {
      const int j0 = sm.s.jl[p],    j1 = sm.s.jl[p+4],  j2 = sm.s.jl[p+8],  j3 = sm.s.jl[p+12];
      const int j4 = sm.s.jl[p+16], j5 = sm.s.jl[p+20], j6 = sm.s.jl[p+24], j7 = sm.s.jl[p+28];
      const float v0 = sm.s.vl[p],    v1 = sm.s.vl[p+4],  v2 = sm.s.vl[p+8],  v3 = sm.s.vl[p+12];
      const float v4 = sm.s.vl[p+16], v5 = sm.s.vl[p+20], v6 = sm.s.vl[p+24], v7 = sm.s.vl[p+28];
      const float2 g0 = x2[j0*64 + lane];
      const float2 g1 = x2[j1*64 + lane];
      const float2 g2 = x2[j2*64 + lane];
      const float2 g3 = x2[j3*64 + lane];
      const float2 g4 = x2[j4*64 + lane];
      const float2 g5 = x2[j5*64 + lane];
      const float2 g6 = x2[j6*64 + lane];
      const float2 g7 = x2[j7*64 + lane];
      acc0 += v0*g0.x; acc1 += v0*g0.y;
      acc0 += v1*g1.x; acc1 += v1*g1.y;
      acc0 += v2*g2.x; acc1 += v2*g2.y;
      acc0 += v3*g3.x; acc1 += v3*g3.y;
      acc0 += v4*g4.x; acc1 += v4*g4.y;
      acc0 += v5*g5.x; acc1 += v5*g5.y;
      acc0 += v6*g6.x; acc1 += v6*g6.y;
      acc0 += v7*g7.x; acc1 += v7*g7.y;
    }
    for (; p < m; p += 4) {
      const int j = sm.s.jl[p]; const float v = sm.s.vl[p];
      const float2 g = x2[j*64 + lane];
      acc0 += v*g.x; acc1 += v*g.y;
    }
  } else {
    for (int j = w*1024; j < (w+1)*1024; ++j) {
      const float v = Lrow[j];
      if (v != 0.f) {
        const float2 g = x2[j*64 + lane];
        acc0 += v*g.x; acc1 += v*g.y;
      }
    }
  }
  sm.s.red[w][lane*2]     = acc0;
  sm.s.red[w][lane*2 + 1] = acc1;
  __syncthreads();
  if (t < 128)
    Hx[row*128 + t] = sm.s.red[0][t] + sm.s.red[1][t] + sm.s.red[2][t] + sm.s.red[3][t];
}

// ---------------------------------------------------------------------------
// Masked-softmax attention body (reuses idx lists from spmm).
__device__ __forceinline__ void attn_body(
    const float* __restrict__ Ld, const float* __restrict__ Lu,
    float* __restrict__ ws, const unsigned short* __restrict__ idxbuf,
    const int* __restrict__ cntbuf, SmemU& sm, const int bx) {
  const int row = bx & (NN - 1);
  const int br  = bx >> 12;
  const float2* __restrict__ U2 = (const float2*)(ws + (br ? US_OFF : UI_OFF));
  float* __restrict__ O = ws + (br ? OS_OFF : OI_OFF);
  const float s1 = ws[S_OFF + (br ? 2*NN : 0) + row];
  const float* __restrict__ s2a = ws + S_OFF + (br ? 3*NN : NN);
  const int cnt = cntbuf[br*NN + row];
  const int t = threadIdx.x;
  const int w = t >> 6, lane = t & 63;

  float acc0 = 0.f, acc1 = 0.f;
  if (cnt > 0 && cnt <= IDX_CAP) {
    const unsigned short* __restrict__ idx = idxbuf + (size_t)(br*NN + row) * IDX_CAP;
    float dpart = 0.f;
    for (int p = t; p < cnt; p += 256) {
      const int j = idx[p];
      const float sc = s1 + s2a[j];
      const float e = expf(sc >= 0.f ? sc : SLOPE * sc);
      sm.a.jl[p] = j; sm.a.el[p] = e; dpart += e;
    }
    sm.a.rsum[t] = dpart;
    __syncthreads();
    if (t < 128) sm.a.rsum[t] += sm.a.rsum[t + 128];
    __syncthreads();
    if (t < 64) {
      float v = sm.a.rsum[t] + sm.a.rsum[t + 64];
      #pragma unroll
      for (int off = 32; off; off >>= 1) v += __shfl_down(v, off);
      if (t == 0) sm.a.dsh[0] = v;
    }
    __syncthreads();
    const float den = sm.a.dsh[0];
    int p = w;
    for (; p + 28 < cnt; p += 32) {
      const int j0 = sm.a.jl[p],    j1 = sm.a.jl[p+4],  j2 = sm.a.jl[p+8],  j3 = sm.a.jl[p+12];
      const int j4 = sm.a.jl[p+16], j5 = sm.a.jl[p+20], j6 = sm.a.jl[p+24], j7 = sm.a.jl[p+28];
      const float e0 = sm.a.el[p],    e1 = sm.a.el[p+4],  e2 = sm.a.el[p+8],  e3 = sm.a.el[p+12];
      const float e4 = sm.a.el[p+16], e5 = sm.a.el[p+20], e6 = sm.a.el[p+24], e7 = sm.a.el[p+28];
      const float2 g0 = U2[j0*64 + lane];
      const float2 g1 = U2[j1*64 + lane];
      const float2 g2 = U2[j2*64 + lane];
      const float2 g3 = U2[j3*64 + lane];
      const float2 g4 = U2[j4*64 + lane];
      const float2 g5 = U2[j5*64 + lane];
      const float2 g6 = U2[j6*64 + lane];
      const float2 g7 = U2[j7*64 + lane];
      acc0 += e0*g0.x; acc1 += e0*g0.y;
      acc0 += e1*g1.x; acc1 += e1*g1.y;
      acc0 += e2*g2.x; acc1 += e2*g2.y;
      acc0 += e3*g3.x; acc1 += e3*g3.y;
      acc0 += e4*g4.x; acc1 += e4*g4.y;
      acc0 += e5*g5.x; acc1 += e5*g5.y;
      acc0 += e6*g6.x; acc1 += e6*g6.y;
      acc0 += e7*g7.x; acc1 += e7*g7.y;
    }
    for (; p < cnt; p += 4) {
      const int j = sm.a.jl[p]; const float e = sm.a.el[p];
      const float2 g = U2[j*64 + lane];
      acc0 += e*g.x; acc1 += e*g.y;
    }
    sm.a.red[w][lane*2]     = acc0;
    sm.a.red[w][lane*2 + 1] = acc1;
    __syncthreads();
    if (t < 128)
      O[row*128 + t] = (sm.a.red[0][t] + sm.a.red[1][t] + sm.a.red[2][t] + sm.a.red[3][t]) / den;
  } else if (cnt == 0) {
    for (int j = w*1024; j < (w+1)*1024; ++j) {
      const float2 g = U2[j*64 + lane];
      acc0 += g.x; acc1 += g.y;
    }
    sm.a.red[w][lane*2]     = acc0;
    sm.a.red[w][lane*2 + 1] = acc1;
    __syncthreads();
    if (t < 128)
      O[row*128 + t] = (sm.a.red[0][t] + sm.a.red[1][t] + sm.a.red[2][t] + sm.a.red[3][t]) * (1.f / NN);
  } else {
    const float* __restrict__ Lrow = (br ? Lu : Ld) + (size_t)row * NN;
    float dp = 0.f;
    for (int j = w*1024; j < (w+1)*1024; ++j) {
      const float v = Lrow[j];
      if (v != 0.f) {
        const float sc = s1 + s2a[j];
        const float e = expf(sc >= 0.f ? sc : SLOPE * sc);
        const float2 g = U2[j*64 + lane];
        acc0 += e*g.x; acc1 += e*g.y;
        dp += e;
      }
    }
    if (lane == 0) sm.a.dsh[w] = dp;
    sm.a.red[w][lane*2]     = acc0;
    sm.a.red[w][lane*2 + 1] = acc1;
    __syncthreads();
    const float den = sm.a.dsh[0] + sm.a.dsh[1] + sm.a.dsh[2] + sm.a.dsh[3];
    if (t < 128)
      O[row*128 + t] = (sm.a.red[0][t] + sm.a.red[1][t] + sm.a.red[2][t] + sm.a.red[3][t]) / den;
  }
}

// ---------------------------------------------------------------------------
// Fusion A: blocks 0..255 run P-GEMM kz 0..3 (long blocks, start first);
// blocks 256..8447 run the sparse spmm scan+gather. Both latency-bound alone;
// co-residency overlaps their stalls.
__global__ __launch_bounds__(256) void k_fusedA(
    const float* __restrict__ Ld, const float* __restrict__ Lu,
    const float* __restrict__ x, const float* __restrict__ P,
    float* __restrict__ ws, unsigned short* __restrict__ idxbuf,
    int* __restrict__ cntbuf, float* __restrict__ zpart) {
  __shared__ SmemU sm;
  if (blockIdx.x < 256) {
    pgemm_body(P, ws + XWH_OFF, zpart, sm, blockIdx.x & 63, blockIdx.x >> 6);
  } else {
    spmm_body(Ld, Lu, x, ws, idxbuf, cntbuf, sm, blockIdx.x - 256);
  }
}

// Fusion B: blocks 0..255 run P-GEMM kz 4..7; blocks 256..8447 run attention.
__global__ __launch_bounds__(256) void k_fusedB(
    const float* __restrict__ Ld, const float* __restrict__ Lu,
    const float* __restrict__ P, float* __restrict__ ws,
    const unsigned short* __restrict__ idxbuf, const int* __restrict__ cntbuf,
    float* __restrict__ zpart) {
  __shared__ SmemU sm;
  if (blockIdx.x < 256) {
    pgemm_body(P, ws + XWH_OFF, zpart, sm, blockIdx.x & 63, (blockIdx.x >> 6) + 4);
  } else {
    attn_body(Ld, Lu, ws, idxbuf, cntbuf, sm, blockIdx.x - 256);
  }
}

// ---------------------------------------------------------------------------
// U-GEMMs: U_irr = x@Wi0 + Hxi@Wi1 ; U_sol = x@Ws0 + Hxs@Ws1.
__global__ __launch_bounds__(256) void k_ugemm(
    const float* __restrict__ x, const float* __restrict__ Wi_w,
    const float* __restrict__ Ws_w, float* __restrict__ ws) {
  const int rb = blockIdx.x;
  const int sel = blockIdx.y;      // 0:U_irr 1:U_sol
  const float* A[2]; const float* W[2]; float* out;
  if (sel == 0) { A[0]=x; W[0]=Wi_w; A[1]=ws+HXI_OFF; W[1]=Wi_w+16384; out=ws+UI_OFF; }
  else          { A[0]=x; W[0]=Ws_w; A[1]=ws+HXS_OFF; W[1]=Ws_w+16384; out=ws+US_OFF; }

  __shared__ __align__(16) float At[32][33];
  __shared__ __align__(16) float Wt[32][132];
  const int t = threadIdx.x;
  const int rg = t >> 4, cg = t & 15;
  const int r0 = rb * 32;
  float acc[2][8];
  #pragma unroll
  for (int i = 0; i < 2; ++i)
    #pragma unroll
    for (int j = 0; j < 8; ++j) acc[i][j] = 0.f;

  for (int ps = 0; ps < 2; ++ps) {
    const float* __restrict__ Ap = A[ps];
    const float* __restrict__ Wp = W[ps];
    for (int k0 = 0; k0 < 128; k0 += 32) {
      __syncthreads();
      {
        const int row = t >> 3, kq = t & 7;
        const float4 av = *(const float4*)&Ap[(r0 + row)*128 + k0 + kq*4];
        At[row][kq*4+0] = av.x; At[row][kq*4+1] = av.y;
        At[row][kq*4+2] = av.z; At[row][kq*4+3] = av.w;
      }
      #pragma unroll
      for (int l = 0; l < 4; ++l) {
        const int idx = t + l*256;
        const int kr = idx >> 5, c4 = idx & 31;
        const float4 wv = *(const float4*)&Wp[(k0 + kr)*128 + c4*4];
        Wt[kr][c4*4+0] = wv.x; Wt[kr][c4*4+1] = wv.y;
        Wt[kr][c4*4+2] = wv.z; Wt[kr][c4*4+3] = wv.w;
      }
      __syncthreads();
      #pragma unroll
      for (int k = 0; k < 32; ++k) {
        const float a0 = At[rg*2 + 0][k];
        const float a1 = At[rg*2 + 1][k];
        const float4 b0 = *(const float4*)&Wt[k][cg*8];
        const float4 b1 = *(const float4*)&Wt[k][cg*8 + 4];
        acc[0][0] += a0*b0.x; acc[0][1] += a0*b0.y; acc[0][2] += a0*b0.z; acc[0][3] += a0*b0.w;
        acc[0][4] += a0*b1.x; acc[0][5] += a0*b1.y; acc[0][6] += a0*b1.z; acc[0][7] += a0*b1.w;
        acc[1][0] += a1*b0.x; acc[1][1] += a1*b0.y; acc[1][2] += a1*b0.z; acc[1][3] += a1*b0.w;
        acc[1][4] += a1*b1.x; acc[1][5] += a1*b1.y; acc[1][6] += a1*b1.z; acc[1][7] += a1*b1.w;
      }
    }
  }
  #pragma unroll
  for (int i = 0; i < 2; ++i) {
    const int r = r0 + rg*2 + i;
    #pragma unroll
    for (int j = 0; j < 8; ++j) out[r*128 + cg*8 + j] = acc[i][j];
  }
}

// ---------------------------------------------------------------------------
// z = O_irr + O_sol + sum_k zpart[k] + b_total
__global__ __launch_bounds__(256) void k_combine(const float* __restrict__ ws,
                                                 float* __restrict__ z) {
  const int i = blockIdx.x * 256 + threadIdx.x;
  const int col = i & 127;
  float acc = ws[BT_OFF + col] + ws[OI_OFF + i] + ws[OS_OFF + i];
  #pragma unroll
  for (int kz = 0; kz < 8; ++kz) acc += ws[ZP_OFF + kz*NN*128 + i];
  z[i] = acc;
}

// ---------------------------------------------------------------------------
extern "C" void kernel_launch(void* const* d_in, const int* in_sizes, int n_in,
                              void* d_out, int out_size, void* d_ws, size_t ws_size,
                              hipStream_t stream) {
  const float* x       = (const float*)d_in[0];
  const float* Lu      = (const float*)d_in[1];
  const float* Ld      = (const float*)d_in[2];
  const float* P       = (const float*)d_in[3];
  const float* Wi_w    = (const float*)d_in[4];
  const float* Wi_b    = (const float*)d_in[5];
  const float* Ws_w    = (const float*)d_in[6];
  const float* Ws_b    = (const float*)d_in[7];
  const float* Wh_w    = (const float*)d_in[8];
  const float* Wh_b    = (const float*)d_in[9];
  const float* att_irr = (const float*)d_in[10];
  const float* att_sol = (const float*)d_in[11];
  float* z  = (float*)d_out;
  float* ws = (float*)d_ws;
  unsigned short* idxbuf = (unsigned short*)((char*)d_ws + IDX_BYTE_OFF);
  int*            cntbuf = (int*)((char*)d_ws + CNT_BYTE_OFF);
  float*          zpart  = ws + ZP_OFF;

  k_prep<<<1, 128, 0, stream>>>(Wi_w, Wi_b, Ws_w, Ws_b, Wh_b, att_irr, att_sol, ws);
  k_pre2<<<1152, 256, 0, stream>>>(x, Wh_w, ws);
  k_fusedA<<<256 + 2*NN, 256, 0, stream>>>(Ld, Lu, x, P, ws, idxbuf, cntbuf, zpart);
  {
    dim3 g(128, 2);
    k_ugemm<<<g, 256, 0, stream>>>(x, Wi_w, Ws_w, ws);
  }
  k_fusedB<<<256 + 2*NN, 256, 0, stream>>>(Ld, Lu, P, ws, idxbuf, cntbuf, zpart);
  k_combine<<<NN * 128 / 256, 256, 0, stream>>>(ws, z);
}

// Round 3
// 373.478 us; speedup vs baseline: 1.6667x; 1.6667x over previous
//
#include <hip/hip_runtime.h>

#define NN 4096
#define IDX_CAP 512
#define SEG_CAP 160
#define SLOPE 0.2f

typedef float f4_t __attribute__((ext_vector_type(4)));

// ---- workspace layout (float offsets unless noted) ----
#define V_OFF     0                        // v1i,v2i,v1s,v2s : 4*128
#define C_OFF     512                      // 4 score constants
#define BT_OFF    516                      // b_total[128]
#define S_OFF     1024                     // s1i,s2i,s1s,s2s : 4*4096
#define HXI_OFF   32768                    // Ld@x   [4096,128]
#define HXS_OFF   (HXI_OFF + NN*128)       // Lu@x
#define UI_OFF    (HXS_OFF + NN*128)       // x@Wi0 + Hxi@Wi1
#define US_OFF    (UI_OFF + NN*128)        // x@Ws0 + Hxs@Ws1
#define XWH_OFF   (US_OFF + NN*128)        // x@Wh
#define OI_OFF    (XWH_OFF + NN*128)       // alpha_irr @ U_irr
#define OS_OFF    (OI_OFF + NN*128)        // alpha_sol @ U_sol
#define ZP_OFF    (OS_OFF + NN*128)        // P@xWh split-K partials: 8 * [4096,128]
#define WS_FLOATS (ZP_OFF + 8*NN*128)
#define IDX_BYTE_OFF ((size_t)WS_FLOATS * 4)                  // u16 idx lists: 2*4096*512
#define CNT_BYTE_OFF (IDX_BYTE_OFF + (size_t)2*NN*IDX_CAP*2)  // int counts: 2*4096
// total ws ≈ 38.2 MiB

// Pad maps: insert 4 floats after every 32 -> float4 reads at stride 8 floats
// drop from 4-way to 2-way bank aliasing (2-way is free, m136).
#define XI(c)   ((c) + (((c) >> 5) << 2))   // [0,128) -> [0,140); 64-col use -> [0,68)

// XCD-aware (row,branch) mapping: dispatch round-robins XCD = bid%8, so put
// branch 0 (irr/Ld) on XCDs 0-3 and branch 1 (sol/Lu) on XCDs 4-7 -> each
// XCD L2 caches only one branch's 2 MB U + shared x.
#define MAP_BR(bid)   (((bid) >> 2) & 1)
#define MAP_ROW(bid)  ((((bid) >> 3) << 2) | ((bid) & 3))

// ---------------------------------------------------------------------------
// Prep: v-vectors so s1[i] = x[i,:]·v + c, b_total.
__global__ __launch_bounds__(128) void k_prep(
    const float* __restrict__ Wi_w, const float* __restrict__ Wi_b,
    const float* __restrict__ Ws_w, const float* __restrict__ Ws_b,
    const float* __restrict__ Wh_b, const float* __restrict__ att_irr,
    const float* __restrict__ att_sol, float* __restrict__ ws) {
  const int t = threadIdx.x;
  float v1i = 0.f, v2i = 0.f, v1s = 0.f, v2s = 0.f;
  for (int j = 0; j < 2; ++j) {
    for (int o = 0; o < 128; ++o) {
      const float wi = Wi_w[j*16384 + t*128 + o];
      const float wv = Ws_w[j*16384 + t*128 + o];
      v1i += wi * att_irr[j*128 + o];
      v2i += wi * att_irr[256 + j*128 + o];
      v1s += wv * att_sol[j*128 + o];
      v2s += wv * att_sol[256 + j*128 + o];
    }
  }
  ws[V_OFF + t]       = v1i;
  ws[V_OFF + 128 + t] = v2i;
  ws[V_OFF + 256 + t] = v1s;
  ws[V_OFF + 384 + t] = v2s;
  ws[BT_OFF + t] = Wi_b[t] + Wi_b[128 + t] + Ws_b[t] + Ws_b[128 + t] + Wh_b[t];
  if (t < 4) {
    const float* bb = (t < 2) ? Wi_b : Ws_b;
    const float* aa = ((t < 2) ? att_irr : att_sol) + ((t & 1) ? 256 : 0);
    float c = 0.f;
    for (int k = 0; k < 256; ++k) c += bb[k] * aa[k];
    ws[C_OFF + t] = c;
  }
}

// ---------------------------------------------------------------------------
// Fused pre-pass: blocks 0..127 compute xWh = x@Wh; blocks 128..1151 scores.
__global__ __launch_bounds__(256) void k_pre2(
    const float* __restrict__ x, const float* __restrict__ Wh_w,
    float* __restrict__ ws) {
  __shared__ __align__(16) float At[32][33];
  __shared__ __align__(16) float Wt[32][144];
  const int t = threadIdx.x;

  if (blockIdx.x < 128) {
    const int rb = blockIdx.x;
    float* out = ws + XWH_OFF;
    const int rg = t >> 4, cg = t & 15;
    const int r0 = rb * 32;
    float acc[2][8];
    #pragma unroll
    for (int i = 0; i < 2; ++i)
      #pragma unroll
      for (int j = 0; j < 8; ++j) acc[i][j] = 0.f;
    for (int k0 = 0; k0 < 128; k0 += 32) {
      __syncthreads();
      {
        const int row = t >> 3, kq = t & 7;
        const float4 av = *(const float4*)&x[(r0 + row)*128 + k0 + kq*4];
        At[row][kq*4+0] = av.x; At[row][kq*4+1] = av.y;
        At[row][kq*4+2] = av.z; At[row][kq*4+3] = av.w;
      }
      #pragma unroll
      for (int l = 0; l < 4; ++l) {
        const int idx = t + l*256;
        const int kr = idx >> 5, c4 = idx & 31;
        const float4 wv = *(const float4*)&Wh_w[(k0 + kr)*128 + c4*4];
        *(float4*)&Wt[kr][XI(c4*4)] = wv;
      }
      __syncthreads();
      #pragma unroll
      for (int k = 0; k < 32; ++k) {
        const float a0 = At[rg*2 + 0][k];
        const float a1 = At[rg*2 + 1][k];
        const float4 b0 = *(const float4*)&Wt[k][XI(cg*8)];
        const float4 b1 = *(const float4*)&Wt[k][XI(cg*8 + 4)];
        acc[0][0] += a0*b0.x; acc[0][1] += a0*b0.y; acc[0][2] += a0*b0.z; acc[0][3] += a0*b0.w;
        acc[0][4] += a0*b1.x; acc[0][5] += a0*b1.y; acc[0][6] += a0*b1.z; acc[0][7] += a0*b1.w;
        acc[1][0] += a1*b0.x; acc[1][1] += a1*b0.y; acc[1][2] += a1*b0.z; acc[1][3] += a1*b0.w;
        acc[1][4] += a1*b1.x; acc[1][5] += a1*b1.y; acc[1][6] += a1*b1.z; acc[1][7] += a1*b1.w;
      }
    }
    #pragma unroll
    for (int i = 0; i < 2; ++i) {
      const int r = r0 + rg*2 + i;
      #pragma unroll
      for (int j = 0; j < 8; ++j) out[r*128 + cg*8 + j] = acc[i][j];
    }
  } else {
    const int wave = t >> 6, lane = t & 63;
    const int row = (blockIdx.x - 128) * 4 + wave;
    const float* v = ws + V_OFF;
    const float x0 = x[row*128 + lane];
    const float x1 = x[row*128 + 64 + lane];
    float p0 = x0 * v[lane]       + x1 * v[64 + lane];
    float p1 = x0 * v[128 + lane] + x1 * v[192 + lane];
    float p2 = x0 * v[256 + lane] + x1 * v[320 + lane];
    float p3 = x0 * v[384 + lane] + x1 * v[448 + lane];
    #pragma unroll
    for (int off = 32; off; off >>= 1) {
      p0 += __shfl_down(p0, off);
      p1 += __shfl_down(p1, off);
      p2 += __shfl_down(p2, off);
      p3 += __shfl_down(p3, off);
    }
    if (lane == 0) {
      ws[S_OFF + row]          = p0 + ws[C_OFF + 0];
      ws[S_OFF + NN + row]     = p1 + ws[C_OFF + 1];
      ws[S_OFF + 2*NN + row]   = p2 + ws[C_OFF + 2];
      ws[S_OFF + 3*NN + row]   = p3 + ws[C_OFF + 3];
    }
  }
}

// ---------------------------------------------------------------------------
// Sparse row pass v4: per-wave register-base compaction, nt scan, float4
// pair-gather (2 nnz per wave-iter, 16 B/lane), XCD-aware branch mapping.
__global__ __launch_bounds__(256) void k_spmm_emit(
    const float* __restrict__ Ld, const float* __restrict__ Lu,
    const float* __restrict__ x, float* __restrict__ ws,
    unsigned short* __restrict__ idxbuf, int* __restrict__ cntbuf) {
  const int bid = blockIdx.x;
  const int br  = MAP_BR(bid);
  const int row = MAP_ROW(bid);
  const float* __restrict__ Lrow = (br ? Lu : Ld) + (size_t)row * NN;
  float* __restrict__ Hx = ws + (br ? HXS_OFF : HXI_OFF);
  unsigned short* __restrict__ idxg = idxbuf + (size_t)(br*NN + row) * IDX_CAP;
  const int t = threadIdx.x;
  const int w = t >> 6, lane = t & 63;
  const unsigned long long lmask = (1ull << lane) - 1ull;

  __shared__ short jseg[4][SEG_CAP];
  __shared__ float vseg[4][SEG_CAP];
  __shared__ int   wcnt[4];
  __shared__ int   off[5];
  __shared__ short jl[IDX_CAP];
  __shared__ float vl[IDX_CAP];
  __shared__ float red[4][128];

  // ---- scan 16 KB row: 4 nt float4 per thread ----
  const f4_t* __restrict__ Lrow4 = (const f4_t*)Lrow;
  f4_t lv[4];
  #pragma unroll
  for (int i = 0; i < 4; ++i) lv[i] = __builtin_nontemporal_load(&Lrow4[i*256 + t]);

  int base = 0;
  #pragma unroll
  for (int i = 0; i < 4; ++i) {
    #pragma unroll
    for (int c = 0; c < 4; ++c) {
      const float v = lv[i][c];
      const unsigned long long bm = __ballot(v != 0.f);
      if (v != 0.f) {
        const int pos = base + (int)__popcll(bm & lmask);
        if (pos < SEG_CAP) {
          jseg[w][pos] = (short)((i*256 + t)*4 + c);
          vseg[w][pos] = v;
        }
      }
      base += (int)__popcll(bm);
    }
  }
  if (lane == 0) wcnt[w] = base;
  __syncthreads();
  if (t == 0) {
    int o = 0, ov = 0;
    #pragma unroll
    for (int s = 0; s < 4; ++s) { off[s] = o; ov |= (wcnt[s] > SEG_CAP); o += wcnt[s]; }
    off[4] = (ov || o > IDX_CAP) ? (IDX_CAP + 1) : o;
    cntbuf[br*NN + row] = off[4];
  }
  __syncthreads();
  const int m = off[4];

  if (m <= IDX_CAP) {
    const int o = off[w], c = wcnt[w];
    for (int k = lane; k < c; k += 64) {
      const short j = jseg[w][k];
      jl[o + k] = j;
      vl[o + k] = vseg[w][k];
      idxg[o + k] = (unsigned short)j;
    }
  }
  __syncthreads();

  if (m <= IDX_CAP) {
    // ---- gather: float4/lane, 2 nnz per wave-iter (halves of the wave) ----
    const f4_t* __restrict__ x4 = (const f4_t*)x;
    const int li = lane & 31, half = lane >> 5;
    f4_t acc = {0.f, 0.f, 0.f, 0.f};
    int p = w;   // pair index; wave w owns pairs == w (mod 4)
    for (; 2*(p + 12) + 1 < m; p += 16) {
      const int q0 = 2*p + half, q1 = 2*(p+4) + half,
                q2 = 2*(p+8) + half, q3 = 2*(p+12) + half;
      const int j0 = jl[q0], j1 = jl[q1], j2 = jl[q2], j3 = jl[q3];
      const float v0 = vl[q0], v1 = vl[q1], v2 = vl[q2], v3 = vl[q3];
      const f4_t g0 = x4[j0*32 + li];
      const f4_t g1 = x4[j1*32 + li];
      const f4_t g2 = x4[j2*32 + li];
      const f4_t g3 = x4[j3*32 + li];
      acc += v0*g0; acc += v1*g1; acc += v2*g2; acc += v3*g3;
    }
    for (; 2*p < m; p += 4) {
      const int q = 2*p + half;
      if (q < m) acc += vl[q] * x4[jl[q]*32 + li];
    }
    #pragma unroll
    for (int c = 0; c < 4; ++c) acc[c] += __shfl_xor(acc[c], 32);
    if (half == 0) {
      red[w][li*4+0] = acc[0]; red[w][li*4+1] = acc[1];
      red[w][li*4+2] = acc[2]; red[w][li*4+3] = acc[3];
    }
  } else {
    // overflow fallback (statistically impossible at 5%): dense rescan
    const float2* __restrict__ x2 = (const float2*)x;
    float acc0 = 0.f, acc1 = 0.f;
    for (int j = w*1024; j < (w+1)*1024; ++j) {
      const float v = Lrow[j];
      if (v != 0.f) {
        const float2 g = x2[j*64 + lane];
        acc0 += v*g.x; acc1 += v*g.y;
      }
    }
    red[w][lane*2]     = acc0;
    red[w][lane*2 + 1] = acc1;
  }
  __syncthreads();
  if (t < 128)
    Hx[row*128 + t] = red[0][t] + red[1][t] + red[2][t] + red[3][t];
}

// ---------------------------------------------------------------------------
// U-GEMMs: U_irr = x@Wi0 + Hxi@Wi1 ; U_sol = x@Ws0 + Hxs@Ws1 (padded Wt).
__global__ __launch_bounds__(256) void k_ugemm(
    const float* __restrict__ x, const float* __restrict__ Wi_w,
    const float* __restrict__ Ws_w, float* __restrict__ ws) {
  const int rb = blockIdx.x;
  const int sel = blockIdx.y;      // 0:U_irr 1:U_sol
  const float* A[2]; const float* W[2]; float* out;
  if (sel == 0) { A[0]=x; W[0]=Wi_w; A[1]=ws+HXI_OFF; W[1]=Wi_w+16384; out=ws+UI_OFF; }
  else          { A[0]=x; W[0]=Ws_w; A[1]=ws+HXS_OFF; W[1]=Ws_w+16384; out=ws+US_OFF; }

  __shared__ __align__(16) float At[32][33];
  __shared__ __align__(16) float Wt[32][144];
  const int t = threadIdx.x;
  const int rg = t >> 4, cg = t & 15;
  const int r0 = rb * 32;
  float acc[2][8];
  #pragma unroll
  for (int i = 0; i < 2; ++i)
    #pragma unroll
    for (int j = 0; j < 8; ++j) acc[i][j] = 0.f;

  for (int ps = 0; ps < 2; ++ps) {
    const float* __restrict__ Ap = A[ps];
    const float* __restrict__ Wp = W[ps];
    for (int k0 = 0; k0 < 128; k0 += 32) {
      __syncthreads();
      {
        const int row = t >> 3, kq = t & 7;
        const float4 av = *(const float4*)&Ap[(r0 + row)*128 + k0 + kq*4];
        At[row][kq*4+0] = av.x; At[row][kq*4+1] = av.y;
        At[row][kq*4+2] = av.z; At[row][kq*4+3] = av.w;
      }
      #pragma unroll
      for (int l = 0; l < 4; ++l) {
        const int idx = t + l*256;
        const int kr = idx >> 5, c4 = idx & 31;
        const float4 wv = *(const float4*)&Wp[(k0 + kr)*128 + c4*4];
        *(float4*)&Wt[kr][XI(c4*4)] = wv;
      }
      __syncthreads();
      #pragma unroll
      for (int k = 0; k < 32; ++k) {
        const float a0 = At[rg*2 + 0][k];
        const float a1 = At[rg*2 + 1][k];
        const float4 b0 = *(const float4*)&Wt[k][XI(cg*8)];
        const float4 b1 = *(const float4*)&Wt[k][XI(cg*8 + 4)];
        acc[0][0] += a0*b0.x; acc[0][1] += a0*b0.y; acc[0][2] += a0*b0.z; acc[0][3] += a0*b0.w;
        acc[0][4] += a0*b1.x; acc[0][5] += a0*b1.y; acc[0][6] += a0*b1.z; acc[0][7] += a0*b1.w;
        acc[1][0] += a1*b0.x; acc[1][1] += a1*b0.y; acc[1][2] += a1*b0.z; acc[1][3] += a1*b0.w;
        acc[1][4] += a1*b1.x; acc[1][5] += a1*b1.y; acc[1][6] += a1*b1.z; acc[1][7] += a1*b1.w;
      }
    }
  }
  #pragma unroll
  for (int i = 0; i < 2; ++i) {
    const int r = r0 + rg*2 + i;
    #pragma unroll
    for (int j = 0; j < 8; ++j) out[r*128 + cg*8 + j] = acc[i][j];
  }
}

// ---------------------------------------------------------------------------
// Masked-softmax attention v4: float4 pair-gather + XCD-aware branch mapping.
__global__ __launch_bounds__(256) void k_attn(
    const float* __restrict__ Ld, const float* __restrict__ Lu,
    float* __restrict__ ws, const unsigned short* __restrict__ idxbuf,
    const int* __restrict__ cntbuf) {
  const int bid = blockIdx.x;
  const int br  = MAP_BR(bid);
  const int row = MAP_ROW(bid);
  const float* __restrict__ U = ws + (br ? US_OFF : UI_OFF);
  float* __restrict__ O = ws + (br ? OS_OFF : OI_OFF);
  const float s1 = ws[S_OFF + (br ? 2*NN : 0) + row];
  const float* __restrict__ s2a = ws + S_OFF + (br ? 3*NN : NN);
  const int cnt = cntbuf[br*NN + row];
  const int t = threadIdx.x;
  const int w = t >> 6, lane = t & 63;

  __shared__ int   jl[IDX_CAP];
  __shared__ float el[IDX_CAP];
  __shared__ float red[4][128];
  __shared__ float rsum[256];
  __shared__ float dsh[4];

  if (cnt > 0 && cnt <= IDX_CAP) {
    const unsigned short* __restrict__ idx = idxbuf + (size_t)(br*NN + row) * IDX_CAP;
    float dpart = 0.f;
    for (int p = t; p < cnt; p += 256) {
      const int j = idx[p];
      const float sc = s1 + s2a[j];
      const float e = expf(sc >= 0.f ? sc : SLOPE * sc);
      jl[p] = j; el[p] = e; dpart += e;
    }
    rsum[t] = dpart;
    __syncthreads();
    if (t < 128) rsum[t] += rsum[t + 128];
    __syncthreads();
    if (t < 64) {
      float v = rsum[t] + rsum[t + 64];
      #pragma unroll
      for (int off = 32; off; off >>= 1) v += __shfl_down(v, off);
      if (t == 0) dsh[0] = v;
    }
    __syncthreads();
    const float den = dsh[0];
    // ---- gather: float4/lane, 2 nnz per wave-iter ----
    const f4_t* __restrict__ U4 = (const f4_t*)U;
    const int li = lane & 31, half = lane >> 5;
    f4_t acc = {0.f, 0.f, 0.f, 0.f};
    int p = w;
    for (; 2*(p + 12) + 1 < cnt; p += 16) {
      const int q0 = 2*p + half, q1 = 2*(p+4) + half,
                q2 = 2*(p+8) + half, q3 = 2*(p+12) + half;
      const int j0 = jl[q0], j1 = jl[q1], j2 = jl[q2], j3 = jl[q3];
      const float e0 = el[q0], e1 = el[q1], e2 = el[q2], e3 = el[q3];
      const f4_t g0 = U4[j0*32 + li];
      const f4_t g1 = U4[j1*32 + li];
      const f4_t g2 = U4[j2*32 + li];
      const f4_t g3 = U4[j3*32 + li];
      acc += e0*g0; acc += e1*g1; acc += e2*g2; acc += e3*g3;
    }
    for (; 2*p < cnt; p += 4) {
      const int q = 2*p + half;
      if (q < cnt) acc += el[q] * U4[jl[q]*32 + li];
    }
    #pragma unroll
    for (int c = 0; c < 4; ++c) acc[c] += __shfl_xor(acc[c], 32);
    if (half == 0) {
      red[w][li*4+0] = acc[0]; red[w][li*4+1] = acc[1];
      red[w][li*4+2] = acc[2]; red[w][li*4+3] = acc[3];
    }
    __syncthreads();
    if (t < 128)
      O[row*128 + t] = (red[0][t] + red[1][t] + red[2][t] + red[3][t]) / den;
  } else if (cnt == 0) {
    // all-masked row -> uniform 1/N (never hit at 5%)
    const float2* __restrict__ U2 = (const float2*)U;
    float acc0 = 0.f, acc1 = 0.f;
    for (int j = w*1024; j < (w+1)*1024; ++j) {
      const float2 g = U2[j*64 + lane];
      acc0 += g.x; acc1 += g.y;
    }
    red[w][lane*2]     = acc0;
    red[w][lane*2 + 1] = acc1;
    __syncthreads();
    if (t < 128)
      O[row*128 + t] = (red[0][t] + red[1][t] + red[2][t] + red[3][t]) * (1.f / NN);
  } else {
    // overflowed index cap: dense rescan
    const float* __restrict__ Lrow = (br ? Lu : Ld) + (size_t)row * NN;
    const float2* __restrict__ U2 = (const float2*)U;
    float acc0 = 0.f, acc1 = 0.f, dp = 0.f;
    for (int j = w*1024; j < (w+1)*1024; ++j) {
      const float v = Lrow[j];
      if (v != 0.f) {
        const float sc = s1 + s2a[j];
        const float e = expf(sc >= 0.f ? sc : SLOPE * sc);
        const float2 g = U2[j*64 + lane];
        acc0 += e*g.x; acc1 += e*g.y;
        dp += e;
      }
    }
    if (lane == 0) dsh[w] = dp;
    red[w][lane*2]     = acc0;
    red[w][lane*2 + 1] = acc1;
    __syncthreads();
    const float den = dsh[0] + dsh[1] + dsh[2] + dsh[3];
    if (t < 128)
      O[row*128 + t] = (red[0][t] + red[1][t] + red[2][t] + red[3][t]) / den;
  }
}

// ---------------------------------------------------------------------------
// Dense P @ xWh, BM=64, BN=64, split-K=8 -> 1024 blocks (4/CU), padded Xt.
__global__ __launch_bounds__(256) void k_pgemm(const float* __restrict__ P,
                                               const float* __restrict__ ws,
                                               float* __restrict__ zpart) {
  const int rbl = blockIdx.x & 63;   // 64 row-blocks of 64
  const int nb  = blockIdx.x >> 6;   // 2 col-blocks of 64
  const int kz  = blockIdx.y;        // 8 K-splits of 512
  const float* __restrict__ Xw = ws + XWH_OFF;

  __shared__ __align__(16) float Pt[64][33];
  __shared__ __align__(16) float Xt[32][72];
  const int t = threadIdx.x;
  const int rg = t >> 4, cg = t & 15;   // 16 x 4 rows, 16 x 4 cols
  const int r0 = rbl * 64;
  const int c0 = nb * 64;
  const int kbase = kz * 512;
  float acc[4][4];
  #pragma unroll
  for (int i = 0; i < 4; ++i)
    #pragma unroll
    for (int j = 0; j < 4; ++j) acc[i][j] = 0.f;

  for (int k0 = kbase; k0 < kbase + 512; k0 += 32) {
    __syncthreads();
    #pragma unroll
    for (int l = 0; l < 2; ++l) { // stage P: 64x32
      const int idx = t + l*256;
      const int row = idx >> 3, kq = idx & 7;
      const float4 pv = *(const float4*)&P[(size_t)(r0 + row)*NN + k0 + kq*4];
      Pt[row][kq*4+0] = pv.x; Pt[row][kq*4+1] = pv.y;
      Pt[row][kq*4+2] = pv.z; Pt[row][kq*4+3] = pv.w;
    }
    { // stage xWh slab: 32x64 (padded layout), 2 float4/thread
      #pragma unroll
      for (int l = 0; l < 2; ++l) {
        const int idx = t + l*256;
        const int kr = idx >> 4, c4 = idx & 15;
        const float4 xv = *(const float4*)&Xw[(k0 + kr)*128 + c0 + c4*4];
        *(float4*)&Xt[kr][XI(c4*4)] = xv;
      }
    }
    __syncthreads();
    #pragma unroll
    for (int k = 0; k < 32; ++k) {
      const float a0 = Pt[rg*4 + 0][k];
      const float a1 = Pt[rg*4 + 1][k];
      const float a2 = Pt[rg*4 + 2][k];
      const float a3 = Pt[rg*4 + 3][k];
      const float4 b = *(const float4*)&Xt[k][XI(cg*4)];
      acc[0][0] += a0*b.x; acc[0][1] += a0*b.y; acc[0][2] += a0*b.z; acc[0][3] += a0*b.w;
      acc[1][0] += a1*b.x; acc[1][1] += a1*b.y; acc[1][2] += a1*b.z; acc[1][3] += a1*b.w;
      acc[2][0] += a2*b.x; acc[2][1] += a2*b.y; acc[2][2] += a2*b.z; acc[2][3] += a2*b.w;
      acc[3][0] += a3*b.x; acc[3][1] += a3*b.y; acc[3][2] += a3*b.z; acc[3][3] += a3*b.w;
    }
  }
  float* __restrict__ zp = zpart + (size_t)kz * NN * 128;
  #pragma unroll
  for (int i = 0; i < 4; ++i) {
    const int r = r0 + rg*4 + i;
    #pragma unroll
    for (int j = 0; j < 4; ++j) zp[r*128 + c0 + cg*4 + j] = acc[i][j];
  }
}

// ---------------------------------------------------------------------------
// z = O_irr + O_sol + sum_k zpart[k] + b_total
__global__ __launch_bounds__(256) void k_combine(const float* __restrict__ ws,
                                                 float* __restrict__ z) {
  const int i = blockIdx.x * 256 + threadIdx.x;
  const int col = i & 127;
  float acc = ws[BT_OFF + col] + ws[OI_OFF + i] + ws[OS_OFF + i];
  #pragma unroll
  for (int kz = 0; kz < 8; ++kz) acc += ws[ZP_OFF + kz*NN*128 + i];
  z[i] = acc;
}

// ---------------------------------------------------------------------------
extern "C" void kernel_launch(void* const* d_in, const int* in_sizes, int n_in,
                              void* d_out, int out_size, void* d_ws, size_t ws_size,
                              hipStream_t stream) {
  const float* x       = (const float*)d_in[0];
  const float* Lu      = (const float*)d_in[1];
  const float* Ld      = (const float*)d_in[2];
  const float* P       = (const float*)d_in[3];
  const float* Wi_w    = (const float*)d_in[4];
  const float* Wi_b    = (const float*)d_in[5];
  const float* Ws_w    = (const float*)d_in[6];
  const float* Ws_b    = (const float*)d_in[7];
  const float* Wh_w    = (const float*)d_in[8];
  const float* Wh_b    = (const float*)d_in[9];
  const float* att_irr = (const float*)d_in[10];
  const float* att_sol = (const float*)d_in[11];
  float* z  = (float*)d_out;
  float* ws = (float*)d_ws;
  unsigned short* idxbuf = (unsigned short*)((char*)d_ws + IDX_BYTE_OFF);
  int*            cntbuf = (int*)((char*)d_ws + CNT_BYTE_OFF);
  float*          zpart  = ws + ZP_OFF;

  k_prep<<<1, 128, 0, stream>>>(Wi_w, Wi_b, Ws_w, Ws_b, Wh_b, att_irr, att_sol, ws);
  k_pre2<<<1152, 256, 0, stream>>>(x, Wh_w, ws);
  k_spmm_emit<<<2 * NN, 256, 0, stream>>>(Ld, Lu, x, ws, idxbuf, cntbuf);
  {
    dim3 g(128, 2);
    k_ugemm<<<g, 256, 0, stream>>>(x, Wi_w, Ws_w, ws);
  }
  k_attn<<<2 * NN, 256, 0, stream>>>(Ld, Lu, ws, idxbuf, cntbuf);
  {
    dim3 g(128, 8);
    k_pgemm<<<g, 256, 0, stream>>>(P, ws, zpart);
  }
  k_combine<<<NN * 128 / 256, 256, 0, stream>>>(ws, z);
}